// Round 19
// baseline (402.087 us; speedup 1.0000x reference)
//
#include <hip/hip_runtime.h>
#include <stdint.h>

#define TC 2
#define CHUNK_BYTES 4096
#define CHUNK_F4 256

typedef float floatx4 __attribute__((ext_vector_type(4)));

// ---------- helpers ----------
static __device__ __forceinline__ float softmax32_l2(float z)
{
  float zm = z;
  zm = fmaxf(zm, __shfl_xor(zm, 16));
  zm = fmaxf(zm, __shfl_xor(zm, 8));
  zm = fmaxf(zm, __shfl_xor(zm, 4));
  zm = fmaxf(zm, __shfl_xor(zm, 2));
  zm = fmaxf(zm, __shfl_xor(zm, 1));
  float p = exp2f(z - zm);
  float ps = p;
  ps += __shfl_xor(ps, 16);
  ps += __shfl_xor(ps, 8);
  ps += __shfl_xor(ps, 4);
  ps += __shfl_xor(ps, 2);
  ps += __shfl_xor(ps, 1);
  return p / ps;
}

static __device__ __forceinline__ uint32_t pkbf(float a, float b)
{
  uint32_t ua = __float_as_uint(a), ub = __float_as_uint(b);
  ua = (ua + 0x7FFFu + ((ua >> 16) & 1u)) >> 16;
  ub = (ub + 0x7FFFu + ((ub >> 16) & 1u)) & 0xFFFF0000u;
  return ua | ub;
}

static __device__ __forceinline__ float rfl(float x)
{
  return __int_as_float(__builtin_amdgcn_readfirstlane(__float_as_int(x)));
}

#define RLF(x, i) __int_as_float(__builtin_amdgcn_readlane(__float_as_int(x), (i)))

// dual half-dot against wave-uniform e broadcast; select by half h
static __device__ __forceinline__ float dot16_rl(const float* w, float e, int h)
{
  float a0, a1, a2, a3, b0, b1, b2, b3;
  a0 = w[0]  * RLF(e, 0)  + w[1]  * RLF(e, 1);
  a1 = w[2]  * RLF(e, 2)  + w[3]  * RLF(e, 3);
  a2 = w[4]  * RLF(e, 4)  + w[5]  * RLF(e, 5);
  a3 = w[6]  * RLF(e, 6)  + w[7]  * RLF(e, 7);
  a0 += w[8]  * RLF(e, 8)  + w[9]  * RLF(e, 9);
  a1 += w[10] * RLF(e, 10) + w[11] * RLF(e, 11);
  a2 += w[12] * RLF(e, 12) + w[13] * RLF(e, 13);
  a3 += w[14] * RLF(e, 14) + w[15] * RLF(e, 15);
  float dlo = (a0 + a1) + (a2 + a3);
  b0 = w[0]  * RLF(e, 16) + w[1]  * RLF(e, 17);
  b1 = w[2]  * RLF(e, 18) + w[3]  * RLF(e, 19);
  b2 = w[4]  * RLF(e, 20) + w[5]  * RLF(e, 21);
  b3 = w[6]  * RLF(e, 22) + w[7]  * RLF(e, 23);
  b0 += w[8]  * RLF(e, 24) + w[9]  * RLF(e, 25);
  b1 += w[10] * RLF(e, 26) + w[11] * RLF(e, 27);
  b2 += w[12] * RLF(e, 28) + w[13] * RLF(e, 29);
  b3 += w[14] * RLF(e, 30) + w[15] * RLF(e, 31);
  float dhi = (b0 + b1) + (b2 + b3);
  return h ? dhi : dlo;
}

// ---------- descriptor tables ----------
struct TSeg { const float* pw; uint16_t* PT; int L, Tt, Tpad, fStride, Xtot, dirV, blockBase, nx, ny; };
struct TTable { TSeg s[10]; int nseg; };
struct USeg { const float* U; float* Ut; int fs, nx, ny, L, T, dirV, blockBase; };
struct UTable { USeg s[10]; int nseg; };
struct DSeg { const uint16_t* PT; const float* Ut; float* F; float* B; int chainBase, T, Tt, Tpad; };
struct DTable { DSeg s[10]; int nseg; };
struct MSeg { const float* F; const float* B; const float* Ut; float* out; int L, T, dirV, blockBase, nrx, nfx; };
struct MTable { MSeg s[10]; int nseg; };

// ---------- transpose: pw -> W = 2^(p*igl2) (bf16, exp-domain); nontemporal reads.
// Block index: fixed fastest-varying (DRAM row locality across concurrent blocks).
__global__ __launch_bounds__(256) void k_transpose_all(TTable tbl, const float* __restrict__ gamma)
{
  __shared__ uint16_t tile[128][128];    // 32 KB
  int bid = blockIdx.x;
  int k = 0;
  for (int q = 1; q < tbl.nseg; q++) if (bid >= tbl.s[q].blockBase) k = q;
  TSeg sg = tbl.s[k];
  float igl2 = 1.4426950408889634f / fmaxf(gamma[0], 0.01f);
  int r = bid - sg.blockBase;
  int fixed = r % sg.ny; int tmp = r / sg.ny;
  int jg = tmp & 7; tmp >>= 3;
  int w = tmp % sg.nx;
  int b = tmp / sg.nx;
  int j0 = jg * 4;
  int g = fixed * sg.fStride;
  int a = g & 31;
  int xbase = w * 128 - a;
  if (xbase >= sg.Xtot) return;
  int tid = threadIdx.x;
  int kx = tid & 31, psub = tid >> 5;
  int pstride = sg.L * sg.Tt;
  int clampMax = 2048 * pstride - 4;
  int jthr = j0 + (psub & 3);
  int swj = (jthr >> 1) & 3;
  int gp0 = ((psub >> 2) << 5) + jthr;
  int idx0 = ((b << 10) + gp0) * pstride + (g - a) + (w << 7) + (kx << 2);
  const float* pw = sg.pw;
  #pragma unroll
  for (int hp = 0; hp < 2; hp++) {
    floatx4 st[8];
    #pragma unroll
    for (int q = 0; q < 8; q++) {
      int batch = hp * 8 + q;
      int idx = idx0 + batch * (pstride << 6);
      idx = idx > clampMax ? clampMax : idx;
      st[q] = __builtin_nontemporal_load((const floatx4*)(pw + idx));
    }
    #pragma unroll
    for (int q = 0; q < 8; q++) {
      int batch = hp * 8 + q;
      int i = 2 * batch + (psub >> 2);
      int sw = swj ^ (((i >> 3) & 3) << 2);
      int pl = batch * 8 + psub;
      uint32_t pk0 = pkbf(exp2f(st[q].x * igl2), exp2f(st[q].y * igl2));
      uint32_t pk1 = pkbf(exp2f(st[q].z * igl2), exp2f(st[q].w * igl2));
      if (sw & 1) { uint32_t tswp = pk0; pk0 = pk1; pk1 = tswp; }
      *(uint2*)((unsigned char*)tile + pl * 256 + 8 * (kx ^ (sw >> 1))) = make_uint2(pk0, pk1);
    }
  }
  __syncthreads();
  uint32_t* PTd = (uint32_t*)sg.PT;
  #pragma unroll
  for (int w8 = 0; w8 < 8; w8++) {
    int gidx = w8 * 256 + tid;
    int xs = gidx >> 4;            // 0..127
    int q = gidx & 15;
    int xv = xbase + xs;
    if (xv < 0 || xv >= sg.Xtot) continue;
    int jl = q >> 2, j = j0 + jl;
    int perm3 = (j >> 1) & 7;
    int swjW = (j >> 1) & 3;
    uint32_t pk[4];
    #pragma unroll
    for (int e = 0; e < 4; e++) {
      int wd = ((q & 3) << 2) + e;
      int pos = wd >> 1, pr = wd & 1;
      int i0 = ((pos ^ perm3) << 2) + pr * 2;
      int sw = swjW ^ (((i0 >> 3) & 3) << 2);
      int c = (xs >> 1) ^ sw;
      int u16c = (c << 1) | (xs & 1);
      int r0 = (i0 << 2) + jl;
      uint32_t v0 = tile[r0][u16c];
      uint32_t v1 = tile[r0 + 4][u16c];
      pk[e] = v0 | (v1 << 16);
    }
    int chain, tsl;
    if (sg.dirV) { chain = b * sg.Xtot + xv; tsl = fixed; }
    else         { chain = b * sg.ny + fixed; tsl = xv; }
    *(uint4*)&PTd[((size_t)chain * sg.Tpad + tsl) * 512 + j * 16 + (q & 3) * 4] =
        make_uint4(pk[0], pk[1], pk[2], pk[3]);
  }
}

// ---------- unary transpose: U*igl2 -> Ut[chain][t][c], float4 writes ----------
__global__ __launch_bounds__(256) void k_ut_all(UTable tbl, const float* __restrict__ gamma)
{
  __shared__ float tile[32][33];
  int bid = blockIdx.x;
  int k = 0;
  for (int q = 1; q < tbl.nseg; q++) if (bid >= tbl.s[q].blockBase) k = q;
  USeg sg = tbl.s[k];
  float igl2 = 1.4426950408889634f / fmaxf(gamma[0], 0.01f);
  int r = bid - sg.blockBase;
  int bx = r % sg.nx; int tmp = r / sg.nx;
  int fixed = tmp % sg.ny;
  int b = tmp / sg.ny;
  int tid = threadIdx.x;
  size_t LT = (size_t)sg.L * sg.T;
  int x0 = bx * 32;
  int xx = tid & 31;
  #pragma unroll
  for (int it = 0; it < 4; it++) {
    int c = (tid >> 5) + it * 8;
    tile[xx][c] = sg.U[(size_t)b * 32 * LT + (size_t)c * LT + (size_t)fixed * sg.fs + x0 + xx];
  }
  __syncthreads();
  int xw = tid >> 3;
  int ci = (tid & 7) * 4;
  int chain = sg.dirV ? b * sg.L + x0 + xw : b * sg.L + fixed;
  int tIdx  = sg.dirV ? fixed : x0 + xw;
  float4 vv = make_float4(tile[xw][ci] * igl2, tile[xw][ci + 1] * igl2,
                          tile[xw][ci + 2] * igl2, tile[xw][ci + 3] * igl2);
  *(float4*)&sg.Ut[((size_t)chain * sg.T + tIdx) * 32 + ci] = vv;
}

// ---------- DP (exp-domain, readlane e-broadcast, 1-deep prefetch) ----------
__global__ __launch_bounds__(256) void k_dp_all(DTable tbl, int nDP)
{
  __shared__ __align__(16) unsigned char ldsAll[4][2 * CHUNK_BYTES + 1024];
  int wid = threadIdx.x >> 6;
  unsigned char* lds = ldsAll[wid];
  float* f_out = (float*)(lds + 2 * CHUNK_BYTES);          // 256 floats: output staging
  int gw = blockIdx.x * 4 + wid;
  if (gw >= 2 * nDP) return;
  int isB = (gw >= nDP) ? 1 : 0;
  int bid = gw - isB * nDP;
  int k = 0;
  for (int q = 1; q < tbl.nseg; q++) if (bid >= tbl.s[q].chainBase) k = q;
  DSeg sg = tbl.s[k];
  int chain = bid - sg.chainBase;
  int T = sg.T, Tt = sg.Tt;
  int tid = threadIdx.x & 63, j = tid & 31, h = tid >> 5;
  const float* Utc = sg.Ut + (size_t)chain * T * 32;
  float* Oc = (isB ? sg.B : sg.F) + (size_t)chain * T * 32;
  const float4* src = (const float4*)(sg.PT + (size_t)chain * sg.Tpad * 1024);
  int nch = sg.Tpad / TC;
  int perm3 = (j >> 1) & 7;
  float4 stg[4];
  float uCur[TC], uNxt[TC];
  if (!isB) {
    float cur = Utc[j];
    if (h == 0) f_out[j] = cur;                    // slot 0 (t=0)
    float eCur = exp2f(cur - rfl(cur));
    #pragma unroll
    for (int ss = 0; ss < TC; ss++) {
      int t = ss + 1; t = t > Tt ? Tt : t;
      uCur[ss] = Utc[(size_t)t * 32 + j];
    }
    #pragma unroll
    for (int q = 0; q < 4; q++) stg[q] = src[q * 64 + tid];
    int buf = 0;
    for (int ch = 0; ch < nch; ch++) {
      float4* dst = (float4*)(lds + buf * CHUNK_BYTES);
      #pragma unroll
      for (int q = 0; q < 4; q++) dst[q * 64 + tid] = stg[q];
      if (ch + 1 < nch) {
        const float4* s2 = src + (size_t)(ch + 1) * CHUNK_F4;
        #pragma unroll
        for (int q = 0; q < 4; q++) stg[q] = s2[q * 64 + tid];
        #pragma unroll
        for (int ss = 0; ss < TC; ss++) {
          int t = (ch + 1) * TC + ss + 1; t = t > Tt ? Tt : t;
          uNxt[ss] = Utc[(size_t)t * 32 + j];
        }
      }
      #pragma unroll
      for (int ss = 0; ss < TC; ss++) {
        int s = ch * TC + ss;
        if (s >= Tt) break;
        int t = s + 1;
        const uint32_t* sl = (const uint32_t*)(lds + buf * CHUNK_BYTES + ss * 2048);
        float w[16];
        #pragma unroll
        for (int rr = 0; rr < 4; rr++) {
          int pos = (4 * h + rr) ^ perm3;
          uint2 dv = *(const uint2*)&sl[j * 16 + pos * 2];
          w[rr * 4 + 0] = __uint_as_float(dv.x << 16);
          w[rr * 4 + 1] = __uint_as_float(dv.x & 0xFFFF0000u);
          w[rr * 4 + 2] = __uint_as_float(dv.y << 16);
          w[rr * 4 + 3] = __uint_as_float(dv.y & 0xFFFF0000u);
        }
        float dot = dot16_rl(w, eCur, h);
        float dot2 = dot + __shfl_xor(dot, 32);
        cur = uCur[ss] + __log2f(dot2);
        if (h == 0) f_out[(t & 7) * 32 + j] = cur;
        eCur = exp2f(cur - rfl(cur));
        if ((t & 7) == 7) {
          float4 vv = *(float4*)&f_out[tid * 4];
          *(float4*)&Oc[(size_t)(t - 7) * 32 + tid * 4] = vv;
        }
      }
      #pragma unroll
      for (int ss = 0; ss < TC; ss++) uCur[ss] = uNxt[ss];
      buf ^= 1;
    }
  } else {
    int p2i = j >> 2, pri = (j >> 1) & 1, loi = j & 1;
    float cur = Utc[(size_t)(T - 1) * 32 + j];
    if (h == 0) f_out[7 * 32 + j] = cur;           // slot 7 (t=T-1)
    float eCur = exp2f(cur - rfl(cur));
    #pragma unroll
    for (int ss = 0; ss < TC; ss++) {
      int s = (nch - 1) * TC + ss; s = s > Tt - 1 ? Tt - 1 : s; s = s < 0 ? 0 : s;
      uCur[ss] = Utc[(size_t)s * 32 + j];
    }
    {
      const float4* s2 = src + (size_t)(nch - 1) * CHUNK_F4;
      #pragma unroll
      for (int q = 0; q < 4; q++) stg[q] = s2[q * 64 + tid];
    }
    int buf = 0;
    for (int ch = nch - 1; ch >= 0; ch--) {
      float4* dst = (float4*)(lds + buf * CHUNK_BYTES);
      #pragma unroll
      for (int q = 0; q < 4; q++) dst[q * 64 + tid] = stg[q];
      if (ch > 0) {
        const float4* s2 = src + (size_t)(ch - 1) * CHUNK_F4;
        #pragma unroll
        for (int q = 0; q < 4; q++) stg[q] = s2[q * 64 + tid];
        #pragma unroll
        for (int ss = 0; ss < TC; ss++) {
          int s = (ch - 1) * TC + ss; s = s > Tt - 1 ? Tt - 1 : s; s = s < 0 ? 0 : s;
          uNxt[ss] = Utc[(size_t)s * 32 + j];
        }
      }
      #pragma unroll
      for (int ss = TC - 1; ss >= 0; ss--) {
        int s = ch * TC + ss;
        if (s >= Tt) continue;
        const uint16_t* row16 = (const uint16_t*)(lds + buf * CHUNK_BYTES + ss * 2048);
        float w[16];
        #pragma unroll
        for (int jj = 0; jj < 16; jj++) {
          int u16idx = (16 * h + jj) * 32 + ((p2i ^ (jj >> 1)) * 2 + pri) * 2 + loi;
          w[jj] = __uint_as_float((uint32_t)row16[u16idx] << 16);
        }
        float dot = dot16_rl(w, eCur, h);
        float dot2 = dot + __shfl_xor(dot, 32);
        cur = uCur[ss] + __log2f(dot2);
        if (h == 0) f_out[(s & 7) * 32 + j] = cur;
        eCur = exp2f(cur - rfl(cur));
        if ((s & 7) == 0) {
          float4 vv = *(float4*)&f_out[tid * 4];
          *(float4*)&Oc[(size_t)s * 32 + tid * 4] = vv;
        }
      }
      #pragma unroll
      for (int ss = 0; ss < TC; ss++) uCur[ss] = uNxt[ss];
      buf ^= 1;
    }
  }
}

// ---------- marginals: softmax(F+B-Ut) over c (log2 domain; shifts cancel), float4 write ----------
__global__ __launch_bounds__(256) void k_marg_all(MTable tbl)
{
  __shared__ float sm[32][33];
  int bid = blockIdx.x;
  int k = 0;
  for (int q = 1; q < tbl.nseg; q++) if (bid >= tbl.s[q].blockBase) k = q;
  MSeg sg = tbl.s[k];
  int r = bid - sg.blockBase;
  int rx = r % sg.nrx; int tmp = r / sg.nrx;
  int fx = tmp % sg.nfx; int b = tmp / sg.nfx;
  int tid = threadIdx.x;
  int c = tid & 31;
  int L = sg.L, T = sg.T;
  size_t LT = (size_t)L * T;
  int RA = sg.dirV ? L : T;
  int r0 = rx * 32;
  #pragma unroll
  for (int pass = 0; pass < 4; pass++) {
    int rr = (tid >> 5) + pass * 8;
    int rowAxis = r0 + rr;
    int chain = sg.dirV ? b * L + rowAxis : b * L + fx;
    int t = sg.dirV ? fx : rowAxis;
    size_t idx = ((size_t)chain * T + t) * 32 + c;
    float z = sg.F[idx] + sg.B[idx] - sg.Ut[idx];
    sm[rr][c] = softmax32_l2(z);
  }
  __syncthreads();
  int cc = tid >> 3;
  int xl = (tid & 7) * 4;
  size_t obase = (size_t)b * 32 * LT + (size_t)fx * RA + r0;
  float4 vv = make_float4(sm[xl][cc], sm[xl + 1][cc], sm[xl + 2][cc], sm[xl + 3][cc]);
  *(float4*)&sg.out[obase + (size_t)cc * LT + xl] = vv;
}

// ---------- combine: float4 everywhere ----------
__global__ __launch_bounds__(256) void k_combine(
    const float* __restrict__ uh0, const float* __restrict__ uv0,
    const float* __restrict__ MB, float* __restrict__ out)
{
  int t4 = blockIdx.x * 256 + threadIdx.x;
  int base = t4 * 4;
  int x = base & 127, y = (base >> 7) & 127;
  int bc = base >> 14;
  float4 mh0 = *(const float4*)&MB[base];
  float4 mv0 = *(const float4*)&MB[1048576 + base];
  int ce = 1 + ((y & 1) << 1);
  int coff = bc * 4096 + ((y >> 1) << 6) + (x >> 1);
  const float* cbE = MB + 2097152 + (size_t)(ce - 1) * 524288;
  const float* cbO = cbE + 524288;
  float2 mhcE = *(const float2*)&cbE[coff];
  float2 mhcO = *(const float2*)&cbO[coff];
  float2 mvcE = *(const float2*)&cbE[262144 + coff];
  float2 mvcO = *(const float2*)&cbO[262144 + coff];
  float4 u_h = *(const float4*)&uh0[base];
  float4 u_v = *(const float4*)&uv0[base];
  float mh[4] = {mh0.x, mh0.y, mh0.z, mh0.w};
  float mv[4] = {mv0.x, mv0.y, mv0.z, mv0.w};
  float uh[4] = {u_h.x, u_h.y, u_h.z, u_h.w};
  float uv[4] = {u_v.x, u_v.y, u_v.z, u_v.w};
  float mhc[4] = {mhcE.x, mhcO.x, mhcE.y, mhcO.y};
  float mvc[4] = {mvcE.x, mvcO.x, mvcE.y, mvcO.y};
  float o0[4], o1[4], o2[4], o3[4];
  const float A = 0.0078125f;
  #pragma unroll
  for (int e = 0; e < 4; e++) {
    float mha = mh[e] + mhc[e], mva = mv[e] + mvc[e];
    float avg = (mha + mva) * 0.25f;
    o0[e] = uh[e] - A * (mh[e] - avg);
    o1[e] = uv[e] - A * (mv[e] - avg);
    o2[e] = mha; o3[e] = mva;
  }
  *(float4*)&out[base]           = make_float4(o0[0], o0[1], o0[2], o0[3]);
  *(float4*)&out[1048576 + base] = make_float4(o1[0], o1[1], o1[2], o1[3]);
  *(float4*)&out[2097152 + base] = make_float4(o2[0], o2[1], o2[2], o2[3]);
  *(float4*)&out[3145728 + base] = make_float4(o3[0], o3[1], o3[2], o3[3]);
}

// ---------- launch ----------
static void fill_tseg(TSeg& t, const float* pw, uint16_t* PT, int L, int T, int dirV, int blockBase)
{
  int Tt = T - 1;
  t.pw = pw; t.PT = PT;
  t.L = L; t.Tt = Tt; t.Tpad = T;
  t.fStride = dirV ? L : Tt;
  t.Xtot = dirV ? L : Tt;
  t.dirV = dirV;
  int pad = (t.fStride & 31) ? 31 : 0;
  t.nx = (t.Xtot + pad + 127) / 128;
  t.ny = dirV ? Tt : L;
  t.blockBase = blockBase;
}

extern "C" void kernel_launch(void* const* d_in, const int* in_sizes, int n_in,
                              void* d_out, int out_size, void* d_ws, size_t ws_size,
                              hipStream_t stream)
{
  (void)in_sizes; (void)n_in; (void)out_size; (void)ws_size;
  const float* gamma = (const float*)d_in[20];
  unsigned char* ws = (unsigned char*)d_ws;

  int segL[10], segT[10];
  const float* segPW[10]; const float* segUU[10];
  size_t segMG[10];
  for (int lvl = 0; lvl < 5; lvl++) {
    int H = lvl ? 64 : 128, W = H;
    int si = lvl * 2;
    segL[si] = H; segT[si] = W;
    segPW[si] = (const float*)d_in[lvl * 4 + 2];
    segUU[si] = (const float*)d_in[lvl * 4 + 0];
    segL[si + 1] = W; segT[si + 1] = H;
    segPW[si + 1] = (const float*)d_in[lvl * 4 + 3];
    segUU[si + 1] = (const float*)d_in[lvl * 4 + 1];
    if (lvl == 0) { segMG[0] = 0; segMG[1] = 1048576; }
    else { segMG[si] = 2097152 + (size_t)(lvl - 1) * 524288; segMG[si + 1] = segMG[si] + 262144; }
  }

  uint16_t* PT0 = (uint16_t*)ws;                  // 128 MiB, reused by both phases
  float* MARG = (float*)ws;                       // aliased over PT, used after DP
  float* F0  = (float*)(ws + 268435456ull);
  float* B0  = (float*)(ws + 285212672ull);
  float* Ut0 = (float*)(ws + 301989888ull);

  // global F/B/Ut offsets per segment
  size_t fuOffOf[10];
  {
    size_t fuOff = 0;
    for (int s = 0; s < 10; s++) {
      fuOffOf[s] = fuOff;
      fuOff += (size_t)(2 * segL[s]) * segT[s] * 32;
    }
  }

  // unary transpose for all segments
  UTable ut; ut.nseg = 10;
  int uB = 0;
  for (int s = 0; s < 10; s++) {
    int dirV = s & 1;
    USeg& u = ut.s[s];
    u.U = segUU[s]; u.Ut = Ut0 + fuOffOf[s];
    u.fs = dirV ? segL[s] : segT[s];
    u.nx = (dirV ? segL[s] : segT[s]) / 32;
    u.ny = dirV ? segT[s] : segL[s];
    u.L = segL[s]; u.T = segT[s]; u.dirV = dirV;
    u.blockBase = uB;
    uB += u.nx * u.ny * 2;
  }
  k_ut_all<<<uB, 256, 0, stream>>>(ut, gamma);

  // two phases: {lvl0: segs 0,1}, {lvl1-4: segs 2..9}; PT region reused
  const int phEnd[3] = {0, 2, 10};
  for (int ph = 0; ph < 2; ph++) {
    TTable tt; DTable dt;
    int s0 = phEnd[ph], s1 = phEnd[ph + 1];
    tt.nseg = s1 - s0; dt.nseg = s1 - s0;
    size_t ptOff = 0;
    int tB = 0, cB = 0;
    for (int s = s0; s < s1; s++) {
      int i = s - s0;
      int dirV = s & 1;
      int L = segL[s], T = segT[s];
      int chains = 2 * L;
      fill_tseg(tt.s[i], segPW[s], PT0 + ptOff, L, T, dirV, tB);
      tB += 2 * tt.s[i].ny * tt.s[i].nx * 8;
      DSeg& d = dt.s[i];
      d.PT = PT0 + ptOff; d.Ut = Ut0 + fuOffOf[s];
      d.F = F0 + fuOffOf[s]; d.B = B0 + fuOffOf[s];
      d.chainBase = cB; d.T = T; d.Tt = T - 1; d.Tpad = T;
      cB += chains;
      ptOff += (size_t)chains * T * 1024;
    }
    k_transpose_all<<<tB, 256, 0, stream>>>(tt, gamma);
    k_dp_all<<<(2 * cB + 3) / 4, 256, 0, stream>>>(dt, cB);
  }

  // marginals over all segments
  MTable mt; mt.nseg = 10;
  int mB = 0;
  for (int s = 0; s < 10; s++) {
    int dirV = s & 1;
    MSeg& m = mt.s[s];
    m.F = F0 + fuOffOf[s]; m.B = B0 + fuOffOf[s]; m.Ut = Ut0 + fuOffOf[s];
    m.out = MARG + segMG[s];
    m.L = segL[s]; m.T = segT[s]; m.dirV = dirV;
    m.blockBase = mB;
    m.nrx = (dirV ? segL[s] : segT[s]) / 32;
    m.nfx = dirV ? segT[s] : segL[s];
    mB += 2 * m.nfx * m.nrx;
  }
  k_marg_all<<<mB, 256, 0, stream>>>(mt);
  k_combine<<<1024, 256, 0, stream>>>((const float*)d_in[0], (const float*)d_in[1],
                                      MARG, (float*)d_out);
}

// Round 20
// 366.781 us; speedup vs baseline: 1.0963x; 1.0963x over previous
//
#include <hip/hip_runtime.h>
#include <stdint.h>

#define TC 2
#define CHUNK_BYTES 4096
#define CHUNK_F4 256

typedef float floatx4 __attribute__((ext_vector_type(4)));

// ---------- helpers ----------
static __device__ __forceinline__ float softmax32_l2(float z)
{
  float zm = z;
  zm = fmaxf(zm, __shfl_xor(zm, 16));
  zm = fmaxf(zm, __shfl_xor(zm, 8));
  zm = fmaxf(zm, __shfl_xor(zm, 4));
  zm = fmaxf(zm, __shfl_xor(zm, 2));
  zm = fmaxf(zm, __shfl_xor(zm, 1));
  float p = exp2f(z - zm);
  float ps = p;
  ps += __shfl_xor(ps, 16);
  ps += __shfl_xor(ps, 8);
  ps += __shfl_xor(ps, 4);
  ps += __shfl_xor(ps, 2);
  ps += __shfl_xor(ps, 1);
  return p / ps;
}

static __device__ __forceinline__ uint32_t pkbf(float a, float b)
{
  uint32_t ua = __float_as_uint(a), ub = __float_as_uint(b);
  ua = (ua + 0x7FFFu + ((ua >> 16) & 1u)) >> 16;
  ub = (ub + 0x7FFFu + ((ub >> 16) & 1u)) & 0xFFFF0000u;
  return ua | ub;
}

static __device__ __forceinline__ float rfl(float x)
{
  return __int_as_float(__builtin_amdgcn_readfirstlane(__float_as_int(x)));
}

#define RLF(x, i) __int_as_float(__builtin_amdgcn_readlane(__float_as_int(x), (i)))

// dual half-dot against wave-uniform e broadcast; select by half h
static __device__ __forceinline__ float dot16_rl(const float* w, float e, int h)
{
  float a0, a1, a2, a3, b0, b1, b2, b3;
  a0 = w[0]  * RLF(e, 0)  + w[1]  * RLF(e, 1);
  a1 = w[2]  * RLF(e, 2)  + w[3]  * RLF(e, 3);
  a2 = w[4]  * RLF(e, 4)  + w[5]  * RLF(e, 5);
  a3 = w[6]  * RLF(e, 6)  + w[7]  * RLF(e, 7);
  a0 += w[8]  * RLF(e, 8)  + w[9]  * RLF(e, 9);
  a1 += w[10] * RLF(e, 10) + w[11] * RLF(e, 11);
  a2 += w[12] * RLF(e, 12) + w[13] * RLF(e, 13);
  a3 += w[14] * RLF(e, 14) + w[15] * RLF(e, 15);
  float dlo = (a0 + a1) + (a2 + a3);
  b0 = w[0]  * RLF(e, 16) + w[1]  * RLF(e, 17);
  b1 = w[2]  * RLF(e, 18) + w[3]  * RLF(e, 19);
  b2 = w[4]  * RLF(e, 20) + w[5]  * RLF(e, 21);
  b3 = w[6]  * RLF(e, 22) + w[7]  * RLF(e, 23);
  b0 += w[8]  * RLF(e, 24) + w[9]  * RLF(e, 25);
  b1 += w[10] * RLF(e, 26) + w[11] * RLF(e, 27);
  b2 += w[12] * RLF(e, 28) + w[13] * RLF(e, 29);
  b3 += w[14] * RLF(e, 30) + w[15] * RLF(e, 31);
  float dhi = (b0 + b1) + (b2 + b3);
  return h ? dhi : dlo;
}

// ---------- descriptor tables ----------
struct TSeg { const float* pw; uint16_t* PT; int L, Tt, Tpad, fStride, Xtot, dirV, blockBase, nx, ny; };
struct TTable { TSeg s[10]; int nseg; };
struct USeg { const float* U; float* Ut; int fs, nx, ny, L, T, dirV, blockBase; };
struct UTable { USeg s[10]; int nseg; };
struct DSeg { const uint16_t* PT; const float* Ut; float* F; float* B; int chainBase, T, Tt, Tpad; };
struct DTable { DSeg s[10]; int nseg; };
struct MSeg { const float* F; const float* B; const float* Ut; float* out; int L, T, dirV, blockBase, nrx, nfx; };
struct MTable { MSeg s[10]; int nseg; };

// ---------- transpose: pw -> W = 2^(p*igl2) (bf16, exp-domain); nontemporal pw reads ----------
__global__ __launch_bounds__(256) void k_transpose_all(TTable tbl, const float* __restrict__ gamma)
{
  __shared__ uint16_t tile[128][128];    // 32 KB
  int bid = blockIdx.x;
  int k = 0;
  for (int q = 1; q < tbl.nseg; q++) if (bid >= tbl.s[q].blockBase) k = q;
  TSeg sg = tbl.s[k];
  float igl2 = 1.4426950408889634f / fmaxf(gamma[0], 0.01f);
  int r = bid - sg.blockBase;
  int jg = r & 7; r >>= 3;
  int w = r % sg.nx; int tmp = r / sg.nx;
  int fixed = tmp % sg.ny;
  int b = tmp / sg.ny;
  int j0 = jg * 4;
  int g = fixed * sg.fStride;
  int a = g & 31;
  int xbase = w * 128 - a;
  if (xbase >= sg.Xtot) return;
  int tid = threadIdx.x;
  int kx = tid & 31, psub = tid >> 5;
  int pstride = sg.L * sg.Tt;
  int clampMax = 2048 * pstride - 4;
  int jthr = j0 + (psub & 3);
  int swj = (jthr >> 1) & 3;
  int gp0 = ((psub >> 2) << 5) + jthr;
  int idx0 = ((b << 10) + gp0) * pstride + (g - a) + (w << 7) + (kx << 2);
  const float* pw = sg.pw;
  #pragma unroll
  for (int hp = 0; hp < 2; hp++) {
    floatx4 st[8];
    #pragma unroll
    for (int q = 0; q < 8; q++) {
      int batch = hp * 8 + q;
      int idx = idx0 + batch * (pstride << 6);
      idx = idx > clampMax ? clampMax : idx;
      st[q] = __builtin_nontemporal_load((const floatx4*)(pw + idx));
    }
    #pragma unroll
    for (int q = 0; q < 8; q++) {
      int batch = hp * 8 + q;
      int i = 2 * batch + (psub >> 2);
      int sw = swj ^ (((i >> 3) & 3) << 2);
      int pl = batch * 8 + psub;
      uint32_t pk0 = pkbf(exp2f(st[q].x * igl2), exp2f(st[q].y * igl2));
      uint32_t pk1 = pkbf(exp2f(st[q].z * igl2), exp2f(st[q].w * igl2));
      if (sw & 1) { uint32_t tswp = pk0; pk0 = pk1; pk1 = tswp; }
      *(uint2*)((unsigned char*)tile + pl * 256 + 8 * (kx ^ (sw >> 1))) = make_uint2(pk0, pk1);
    }
  }
  __syncthreads();
  uint32_t* PTd = (uint32_t*)sg.PT;
  #pragma unroll
  for (int w8 = 0; w8 < 8; w8++) {
    int gidx = w8 * 256 + tid;
    int xs = gidx >> 4;            // 0..127
    int q = gidx & 15;
    int xv = xbase + xs;
    if (xv < 0 || xv >= sg.Xtot) continue;
    int jl = q >> 2, j = j0 + jl;
    int perm3 = (j >> 1) & 7;
    int swjW = (j >> 1) & 3;
    uint32_t pk[4];
    #pragma unroll
    for (int e = 0; e < 4; e++) {
      int wd = ((q & 3) << 2) + e;
      int pos = wd >> 1, pr = wd & 1;
      int i0 = ((pos ^ perm3) << 2) + pr * 2;
      int sw = swjW ^ (((i0 >> 3) & 3) << 2);
      int c = (xs >> 1) ^ sw;
      int u16c = (c << 1) | (xs & 1);
      int r0 = (i0 << 2) + jl;
      uint32_t v0 = tile[r0][u16c];
      uint32_t v1 = tile[r0 + 4][u16c];
      pk[e] = v0 | (v1 << 16);
    }
    int chain, tsl;
    if (sg.dirV) { chain = b * sg.Xtot + xv; tsl = fixed; }
    else         { chain = b * sg.ny + fixed; tsl = xv; }
    *(uint4*)&PTd[((size_t)chain * sg.Tpad + tsl) * 512 + j * 16 + (q & 3) * 4] =
        make_uint4(pk[0], pk[1], pk[2], pk[3]);
  }
}

// ---------- unary transpose: U*igl2 -> Ut[chain][t][c], float4 writes ----------
__global__ __launch_bounds__(256) void k_ut_all(UTable tbl, const float* __restrict__ gamma)
{
  __shared__ float tile[32][33];
  int bid = blockIdx.x;
  int k = 0;
  for (int q = 1; q < tbl.nseg; q++) if (bid >= tbl.s[q].blockBase) k = q;
  USeg sg = tbl.s[k];
  float igl2 = 1.4426950408889634f / fmaxf(gamma[0], 0.01f);
  int r = bid - sg.blockBase;
  int bx = r % sg.nx; int tmp = r / sg.nx;
  int fixed = tmp % sg.ny;
  int b = tmp / sg.ny;
  int tid = threadIdx.x;
  size_t LT = (size_t)sg.L * sg.T;
  int x0 = bx * 32;
  int xx = tid & 31;
  #pragma unroll
  for (int it = 0; it < 4; it++) {
    int c = (tid >> 5) + it * 8;
    tile[xx][c] = sg.U[(size_t)b * 32 * LT + (size_t)c * LT + (size_t)fixed * sg.fs + x0 + xx];
  }
  __syncthreads();
  int xw = tid >> 3;
  int ci = (tid & 7) * 4;
  int chain = sg.dirV ? b * sg.L + x0 + xw : b * sg.L + fixed;
  int tIdx  = sg.dirV ? fixed : x0 + xw;
  float4 vv = make_float4(tile[xw][ci] * igl2, tile[xw][ci + 1] * igl2,
                          tile[xw][ci + 2] * igl2, tile[xw][ci + 3] * igl2);
  *(float4*)&sg.Ut[((size_t)chain * sg.T + tIdx) * 32 + ci] = vv;
}

// ---------- DP (exp-domain, readlane e-broadcast, 1-deep prefetch) ----------
__global__ __launch_bounds__(256) void k_dp_all(DTable tbl, int nDP)
{
  __shared__ __align__(16) unsigned char ldsAll[4][2 * CHUNK_BYTES + 1024];
  int wid = threadIdx.x >> 6;
  unsigned char* lds = ldsAll[wid];
  float* f_out = (float*)(lds + 2 * CHUNK_BYTES);          // 256 floats: output staging
  int gw = blockIdx.x * 4 + wid;
  if (gw >= 2 * nDP) return;
  int isB = (gw >= nDP) ? 1 : 0;
  int bid = gw - isB * nDP;
  int k = 0;
  for (int q = 1; q < tbl.nseg; q++) if (bid >= tbl.s[q].chainBase) k = q;
  DSeg sg = tbl.s[k];
  int chain = bid - sg.chainBase;
  int T = sg.T, Tt = sg.Tt;
  int tid = threadIdx.x & 63, j = tid & 31, h = tid >> 5;
  const float* Utc = sg.Ut + (size_t)chain * T * 32;
  float* Oc = (isB ? sg.B : sg.F) + (size_t)chain * T * 32;
  const float4* src = (const float4*)(sg.PT + (size_t)chain * sg.Tpad * 1024);
  int nch = sg.Tpad / TC;
  int perm3 = (j >> 1) & 7;
  float4 stg[4];
  float uCur[TC], uNxt[TC];
  if (!isB) {
    float cur = Utc[j];
    if (h == 0) f_out[j] = cur;                    // slot 0 (t=0)
    float eCur = exp2f(cur - rfl(cur));
    #pragma unroll
    for (int ss = 0; ss < TC; ss++) {
      int t = ss + 1; t = t > Tt ? Tt : t;
      uCur[ss] = Utc[(size_t)t * 32 + j];
    }
    #pragma unroll
    for (int q = 0; q < 4; q++) stg[q] = src[q * 64 + tid];
    int buf = 0;
    for (int ch = 0; ch < nch; ch++) {
      float4* dst = (float4*)(lds + buf * CHUNK_BYTES);
      #pragma unroll
      for (int q = 0; q < 4; q++) dst[q * 64 + tid] = stg[q];
      if (ch + 1 < nch) {
        const float4* s2 = src + (size_t)(ch + 1) * CHUNK_F4;
        #pragma unroll
        for (int q = 0; q < 4; q++) stg[q] = s2[q * 64 + tid];
        #pragma unroll
        for (int ss = 0; ss < TC; ss++) {
          int t = (ch + 1) * TC + ss + 1; t = t > Tt ? Tt : t;
          uNxt[ss] = Utc[(size_t)t * 32 + j];
        }
      }
      #pragma unroll
      for (int ss = 0; ss < TC; ss++) {
        int s = ch * TC + ss;
        if (s >= Tt) break;
        int t = s + 1;
        const uint32_t* sl = (const uint32_t*)(lds + buf * CHUNK_BYTES + ss * 2048);
        float w[16];
        #pragma unroll
        for (int rr = 0; rr < 4; rr++) {
          int pos = (4 * h + rr) ^ perm3;
          uint2 dv = *(const uint2*)&sl[j * 16 + pos * 2];
          w[rr * 4 + 0] = __uint_as_float(dv.x << 16);
          w[rr * 4 + 1] = __uint_as_float(dv.x & 0xFFFF0000u);
          w[rr * 4 + 2] = __uint_as_float(dv.y << 16);
          w[rr * 4 + 3] = __uint_as_float(dv.y & 0xFFFF0000u);
        }
        float dot = dot16_rl(w, eCur, h);
        float dot2 = dot + __shfl_xor(dot, 32);
        cur = uCur[ss] + __log2f(dot2);
        if (h == 0) f_out[(t & 7) * 32 + j] = cur;
        eCur = exp2f(cur - rfl(cur));
        if ((t & 7) == 7) {
          float4 vv = *(float4*)&f_out[tid * 4];
          *(float4*)&Oc[(size_t)(t - 7) * 32 + tid * 4] = vv;
        }
      }
      #pragma unroll
      for (int ss = 0; ss < TC; ss++) uCur[ss] = uNxt[ss];
      buf ^= 1;
    }
  } else {
    int p2i = j >> 2, pri = (j >> 1) & 1, loi = j & 1;
    float cur = Utc[(size_t)(T - 1) * 32 + j];
    if (h == 0) f_out[7 * 32 + j] = cur;           // slot 7 (t=T-1)
    float eCur = exp2f(cur - rfl(cur));
    #pragma unroll
    for (int ss = 0; ss < TC; ss++) {
      int s = (nch - 1) * TC + ss; s = s > Tt - 1 ? Tt - 1 : s; s = s < 0 ? 0 : s;
      uCur[ss] = Utc[(size_t)s * 32 + j];
    }
    {
      const float4* s2 = src + (size_t)(nch - 1) * CHUNK_F4;
      #pragma unroll
      for (int q = 0; q < 4; q++) stg[q] = s2[q * 64 + tid];
    }
    int buf = 0;
    for (int ch = nch - 1; ch >= 0; ch--) {
      float4* dst = (float4*)(lds + buf * CHUNK_BYTES);
      #pragma unroll
      for (int q = 0; q < 4; q++) dst[q * 64 + tid] = stg[q];
      if (ch > 0) {
        const float4* s2 = src + (size_t)(ch - 1) * CHUNK_F4;
        #pragma unroll
        for (int q = 0; q < 4; q++) stg[q] = s2[q * 64 + tid];
        #pragma unroll
        for (int ss = 0; ss < TC; ss++) {
          int s = (ch - 1) * TC + ss; s = s > Tt - 1 ? Tt - 1 : s; s = s < 0 ? 0 : s;
          uNxt[ss] = Utc[(size_t)s * 32 + j];
        }
      }
      #pragma unroll
      for (int ss = TC - 1; ss >= 0; ss--) {
        int s = ch * TC + ss;
        if (s >= Tt) continue;
        const uint16_t* row16 = (const uint16_t*)(lds + buf * CHUNK_BYTES + ss * 2048);
        float w[16];
        #pragma unroll
        for (int jj = 0; jj < 16; jj++) {
          int u16idx = (16 * h + jj) * 32 + ((p2i ^ (jj >> 1)) * 2 + pri) * 2 + loi;
          w[jj] = __uint_as_float((uint32_t)row16[u16idx] << 16);
        }
        float dot = dot16_rl(w, eCur, h);
        float dot2 = dot + __shfl_xor(dot, 32);
        cur = uCur[ss] + __log2f(dot2);
        if (h == 0) f_out[(s & 7) * 32 + j] = cur;
        eCur = exp2f(cur - rfl(cur));
        if ((s & 7) == 0) {
          float4 vv = *(float4*)&f_out[tid * 4];
          *(float4*)&Oc[(size_t)s * 32 + tid * 4] = vv;
        }
      }
      #pragma unroll
      for (int ss = 0; ss < TC; ss++) uCur[ss] = uNxt[ss];
      buf ^= 1;
    }
  }
}

// ---------- marginals: softmax(F+B-Ut) over c (log2 domain; shifts cancel), float4 write ----------
__global__ __launch_bounds__(256) void k_marg_all(MTable tbl)
{
  __shared__ float sm[32][33];
  int bid = blockIdx.x;
  int k = 0;
  for (int q = 1; q < tbl.nseg; q++) if (bid >= tbl.s[q].blockBase) k = q;
  MSeg sg = tbl.s[k];
  int r = bid - sg.blockBase;
  int rx = r % sg.nrx; int tmp = r / sg.nrx;
  int fx = tmp % sg.nfx; int b = tmp / sg.nfx;
  int tid = threadIdx.x;
  int c = tid & 31;
  int L = sg.L, T = sg.T;
  size_t LT = (size_t)L * T;
  int RA = sg.dirV ? L : T;
  int r0 = rx * 32;
  #pragma unroll
  for (int pass = 0; pass < 4; pass++) {
    int rr = (tid >> 5) + pass * 8;
    int rowAxis = r0 + rr;
    int chain = sg.dirV ? b * L + rowAxis : b * L + fx;
    int t = sg.dirV ? fx : rowAxis;
    size_t idx = ((size_t)chain * T + t) * 32 + c;
    float z = sg.F[idx] + sg.B[idx] - sg.Ut[idx];
    sm[rr][c] = softmax32_l2(z);
  }
  __syncthreads();
  int cc = tid >> 3;
  int xl = (tid & 7) * 4;
  size_t obase = (size_t)b * 32 * LT + (size_t)fx * RA + r0;
  float4 vv = make_float4(sm[xl][cc], sm[xl + 1][cc], sm[xl + 2][cc], sm[xl + 3][cc]);
  *(float4*)&sg.out[obase + (size_t)cc * LT + xl] = vv;
}

// ---------- combine: float4 everywhere ----------
__global__ __launch_bounds__(256) void k_combine(
    const float* __restrict__ uh0, const float* __restrict__ uv0,
    const float* __restrict__ MB, float* __restrict__ out)
{
  int t4 = blockIdx.x * 256 + threadIdx.x;
  int base = t4 * 4;
  int x = base & 127, y = (base >> 7) & 127;
  int bc = base >> 14;
  float4 mh0 = *(const float4*)&MB[base];
  float4 mv0 = *(const float4*)&MB[1048576 + base];
  int ce = 1 + ((y & 1) << 1);
  int coff = bc * 4096 + ((y >> 1) << 6) + (x >> 1);
  const float* cbE = MB + 2097152 + (size_t)(ce - 1) * 524288;
  const float* cbO = cbE + 524288;
  float2 mhcE = *(const float2*)&cbE[coff];
  float2 mhcO = *(const float2*)&cbO[coff];
  float2 mvcE = *(const float2*)&cbE[262144 + coff];
  float2 mvcO = *(const float2*)&cbO[262144 + coff];
  float4 u_h = *(const float4*)&uh0[base];
  float4 u_v = *(const float4*)&uv0[base];
  float mh[4] = {mh0.x, mh0.y, mh0.z, mh0.w};
  float mv[4] = {mv0.x, mv0.y, mv0.z, mv0.w};
  float uh[4] = {u_h.x, u_h.y, u_h.z, u_h.w};
  float uv[4] = {u_v.x, u_v.y, u_v.z, u_v.w};
  float mhc[4] = {mhcE.x, mhcO.x, mhcE.y, mhcO.y};
  float mvc[4] = {mvcE.x, mvcO.x, mvcE.y, mvcO.y};
  float o0[4], o1[4], o2[4], o3[4];
  const float A = 0.0078125f;
  #pragma unroll
  for (int e = 0; e < 4; e++) {
    float mha = mh[e] + mhc[e], mva = mv[e] + mvc[e];
    float avg = (mha + mva) * 0.25f;
    o0[e] = uh[e] - A * (mh[e] - avg);
    o1[e] = uv[e] - A * (mv[e] - avg);
    o2[e] = mha; o3[e] = mva;
  }
  *(float4*)&out[base]           = make_float4(o0[0], o0[1], o0[2], o0[3]);
  *(float4*)&out[1048576 + base] = make_float4(o1[0], o1[1], o1[2], o1[3]);
  *(float4*)&out[2097152 + base] = make_float4(o2[0], o2[1], o2[2], o2[3]);
  *(float4*)&out[3145728 + base] = make_float4(o3[0], o3[1], o3[2], o3[3]);
}

// ---------- launch ----------
static void fill_tseg(TSeg& t, const float* pw, uint16_t* PT, int L, int T, int dirV, int blockBase)
{
  int Tt = T - 1;
  t.pw = pw; t.PT = PT;
  t.L = L; t.Tt = Tt; t.Tpad = T;
  t.fStride = dirV ? L : Tt;
  t.Xtot = dirV ? L : Tt;
  t.dirV = dirV;
  int pad = (t.fStride & 31) ? 31 : 0;
  t.nx = (t.Xtot + pad + 127) / 128;
  t.ny = dirV ? Tt : L;
  t.blockBase = blockBase;
}

extern "C" void kernel_launch(void* const* d_in, const int* in_sizes, int n_in,
                              void* d_out, int out_size, void* d_ws, size_t ws_size,
                              hipStream_t stream)
{
  (void)in_sizes; (void)n_in; (void)out_size; (void)ws_size;
  const float* gamma = (const float*)d_in[20];
  unsigned char* ws = (unsigned char*)d_ws;

  int segL[10], segT[10];
  const float* segPW[10]; const float* segUU[10];
  size_t segMG[10];
  for (int lvl = 0; lvl < 5; lvl++) {
    int H = lvl ? 64 : 128, W = H;
    int si = lvl * 2;
    segL[si] = H; segT[si] = W;
    segPW[si] = (const float*)d_in[lvl * 4 + 2];
    segUU[si] = (const float*)d_in[lvl * 4 + 0];
    segL[si + 1] = W; segT[si + 1] = H;
    segPW[si + 1] = (const float*)d_in[lvl * 4 + 3];
    segUU[si + 1] = (const float*)d_in[lvl * 4 + 1];
    if (lvl == 0) { segMG[0] = 0; segMG[1] = 1048576; }
    else { segMG[si] = 2097152 + (size_t)(lvl - 1) * 524288; segMG[si + 1] = segMG[si] + 262144; }
  }

  uint16_t* PT0 = (uint16_t*)ws;                  // 128 MiB, reused by both phases
  float* MARG = (float*)ws;                       // aliased over PT, used after DP
  float* F0  = (float*)(ws + 268435456ull);
  float* B0  = (float*)(ws + 285212672ull);
  float* Ut0 = (float*)(ws + 301989888ull);

  // global F/B/Ut offsets per segment
  size_t fuOffOf[10];
  {
    size_t fuOff = 0;
    for (int s = 0; s < 10; s++) {
      fuOffOf[s] = fuOff;
      fuOff += (size_t)(2 * segL[s]) * segT[s] * 32;
    }
  }

  // unary transpose for all segments
  UTable ut; ut.nseg = 10;
  int uB = 0;
  for (int s = 0; s < 10; s++) {
    int dirV = s & 1;
    USeg& u = ut.s[s];
    u.U = segUU[s]; u.Ut = Ut0 + fuOffOf[s];
    u.fs = dirV ? segL[s] : segT[s];
    u.nx = (dirV ? segL[s] : segT[s]) / 32;
    u.ny = dirV ? segT[s] : segL[s];
    u.L = segL[s]; u.T = segT[s]; u.dirV = dirV;
    u.blockBase = uB;
    uB += u.nx * u.ny * 2;
  }
  k_ut_all<<<uB, 256, 0, stream>>>(ut, gamma);

  // two phases: {lvl0: segs 0,1}, {lvl1-4: segs 2..9}; PT region reused
  const int phEnd[3] = {0, 2, 10};
  for (int ph = 0; ph < 2; ph++) {
    TTable tt; DTable dt;
    int s0 = phEnd[ph], s1 = phEnd[ph + 1];
    tt.nseg = s1 - s0; dt.nseg = s1 - s0;
    size_t ptOff = 0;
    int tB = 0, cB = 0;
    for (int s = s0; s < s1; s++) {
      int i = s - s0;
      int dirV = s & 1;
      int L = segL[s], T = segT[s];
      int chains = 2 * L;
      fill_tseg(tt.s[i], segPW[s], PT0 + ptOff, L, T, dirV, tB);
      tB += 2 * tt.s[i].ny * tt.s[i].nx * 8;
      DSeg& d = dt.s[i];
      d.PT = PT0 + ptOff; d.Ut = Ut0 + fuOffOf[s];
      d.F = F0 + fuOffOf[s]; d.B = B0 + fuOffOf[s];
      d.chainBase = cB; d.T = T; d.Tt = T - 1; d.Tpad = T;
      cB += chains;
      ptOff += (size_t)chains * T * 1024;
    }
    k_transpose_all<<<tB, 256, 0, stream>>>(tt, gamma);
    k_dp_all<<<(2 * cB + 3) / 4, 256, 0, stream>>>(dt, cB);
  }

  // marginals over all segments
  MTable mt; mt.nseg = 10;
  int mB = 0;
  for (int s = 0; s < 10; s++) {
    int dirV = s & 1;
    MSeg& m = mt.s[s];
    m.F = F0 + fuOffOf[s]; m.B = B0 + fuOffOf[s]; m.Ut = Ut0 + fuOffOf[s];
    m.out = MARG + segMG[s];
    m.L = segL[s]; m.T = segT[s]; m.dirV = dirV;
    m.blockBase = mB;
    m.nrx = (dirV ? segL[s] : segT[s]) / 32;
    m.nfx = dirV ? segT[s] : segL[s];
    mB += 2 * m.nfx * m.nrx;
  }
  k_marg_all<<<mB, 256, 0, stream>>>(mt);
  k_combine<<<1024, 256, 0, stream>>>((const float*)d_in[0], (const float*)d_in[1],
                                      MARG, (float*)d_out);
}